// Round 13
// baseline (393.499 us; speedup 1.0000x reference)
//
#include <hip/hip_runtime.h>
#include <hip/hip_fp16.h>

// Pipeline (all fp16 MFMA, f32 accum):
//   Algebraic fusion (R10): q·k^T = b(Wq^T Wk)e^T + b·w1 + (e·w2) + c0.
//   Merged projection (R11): S_big = b_h @ [Mt|w1|0|Wv]^T + bias  [BT,1408]
//     cols 0..799 = bm' (attn A), cols 800..1407 = v (out B).
//   attn = tanh(NT(S_big[,0:800], e'))  batched ; out = NT(attn, S_big[,800:]).
// GEMM: NT, 128x128 tile, BK=32, T3 minimum-2-phase loop (guide §5.5):
//   iter t: STAGE(buf^1, t+1) FIRST -> ds_read+16 MFMA on buf -> vmcnt(0)
//   -> s_barrier -> sched_barrier(0). Stage is in flight for the whole
//   compute (covered drain), LDS only 32 KB -> ~5 blocks/CU occupancy.
//   Overwrite safety: buf^1 was last read in iter t-1; those ds_reads
//   completed before t-1's MFMAs issued, hence before t-1's barrier.
// XOR-swizzled LDS slots (verified R6): chunk c -> row c>>2, col
// ((c&3)^((c>>3)&3))*8; read lane l row r: chunk r*4 + ((l>>4)^((r>>1)&3)).
// 0 bank conflicts + intact 64B-line write coalescing.
// MODE0 = bijective XCD chunking; MODE1 = batch->XCD co-location.

typedef _Float16 f16x8 __attribute__((ext_vector_type(8)));
typedef _Float16 f16x4 __attribute__((ext_vector_type(4)));
typedef float f32x4 __attribute__((ext_vector_type(4)));

__global__ void cvt8_kernel(const float* __restrict__ src, _Float16* __restrict__ dst,
                            long long n8) {
    long long i = blockIdx.x * (long long)blockDim.x + threadIdx.x;
    const long long stride = gridDim.x * (long long)blockDim.x;
    for (; i < n8; i += stride) {
        const float4 f0 = ((const float4*)src)[2 * i];
        const float4 f1 = ((const float4*)src)[2 * i + 1];
        f16x8 h;
        h[0] = (_Float16)f0.x; h[1] = (_Float16)f0.y; h[2] = (_Float16)f0.z; h[3] = (_Float16)f0.w;
        h[4] = (_Float16)f1.x; h[5] = (_Float16)f1.y; h[6] = (_Float16)f1.z; h[7] = (_Float16)f1.w;
        ((f16x8*)dst)[i] = h;
    }
}

// two f32 [768,768] -> f16 transposed [768,768] (z selects matrix)
__global__ void cvtT2_kernel(const float* __restrict__ s0, _Float16* __restrict__ d0,
                             const float* __restrict__ s1, _Float16* __restrict__ d1) {
    __shared__ float t[32][33];
    const float* src = blockIdx.z ? s1 : s0;
    _Float16* dst = blockIdx.z ? d1 : d0;
    const int bx = blockIdx.x, by = blockIdx.y;
    const int tx = threadIdx.x & 31, ty = threadIdx.x >> 5;
#pragma unroll
    for (int k = 0; k < 4; ++k) {
        const int r = ty + 8 * k;
        t[r][tx] = src[(size_t)(by * 32 + r) * 768 + bx * 32 + tx];
    }
    __syncthreads();
#pragma unroll
    for (int k = 0; k < 4; ++k) {
        const int r = ty + 8 * k;
        dst[(size_t)(bx * 32 + r) * 768 + by * 32 + tx] = (_Float16)t[tx][r];
    }
}

// w1 -> Mt_aug row 768 ; w2f ; bias_mg[1408] ; zero Mt_aug rows 769..799
__global__ void prep_kernel(const _Float16* __restrict__ WqT, const _Float16* __restrict__ WkT,
                            const float* __restrict__ bq, const float* __restrict__ bk,
                            const float* __restrict__ bv,
                            float* __restrict__ w2f, _Float16* __restrict__ Mt_aug,
                            float* __restrict__ bias_mg) {
    const int wid = blockIdx.x * 4 + (threadIdx.x >> 6);
    const int lane = threadIdx.x & 63;
    if (wid < 768) {                 // w1[wid] = WqT[wid,:]·bk
        float s = 0.f;
        for (int k = 0; k < 12; ++k) s += (float)WqT[(size_t)wid * 768 + lane + 64 * k] * bk[lane + 64 * k];
        for (int o = 32; o; o >>= 1) s += __shfl_xor(s, o);
        if (lane == 0) Mt_aug[(size_t)768 * 768 + wid] = (_Float16)s;
    } else if (wid < 1536) {         // w2[n] = WkT[n,:]·bq
        const int n = wid - 768;
        float s = 0.f;
        for (int k = 0; k < 12; ++k) s += (float)WkT[(size_t)n * 768 + lane + 64 * k] * bq[lane + 64 * k];
        for (int o = 32; o; o >>= 1) s += __shfl_xor(s, o);
        if (lane == 0) w2f[n] = s;
    } else if (wid == 1536) {        // c0 -> bias_mg[768], 1 -> [769], 0 -> 770..799
        float s = 0.f;
        for (int k = 0; k < 12; ++k) s += bq[lane + 64 * k] * bk[lane + 64 * k];
        for (int o = 32; o; o >>= 1) s += __shfl_xor(s, o);
        if (lane < 32) {
            float v = 0.f;
            if (lane == 0) v = s;
            if (lane == 1) v = 1.f;
            bias_mg[768 + lane] = v;
        }
    } else if (wid < 1560) {         // bias_mg: zeros 0..767 ; bv -> 800..1376 ; 0 pads
        const int i = (wid - 1537) * 64 + lane;     // [0,1472)
        if (i < 768) bias_mg[i] = 0.f;
        else {
            const int j = i + 32;                   // 800..1503
            if (j < 1408) bias_mg[j] = (j < 1377) ? bv[j - 800] : 0.f;
        }
    } else if (wid < 1591) {         // zero Mt_aug rows 769..799
        const int r = 769 + (wid - 1560);
        for (int k = 0; k < 12; ++k) Mt_aug[(size_t)r * 768 + lane + 64 * k] = (_Float16)0.f;
    }
}

// e f32 [rows,768] -> e' f16 [rows,800]: cvt + col768=1 + col769=e·w2 + 770..799=0
__global__ void cvt_e_aug_kernel(const float* __restrict__ e, const float* __restrict__ w2f,
                                 _Float16* __restrict__ dst, int rows) {
    const int wpb = blockDim.x >> 6;
    int wid = blockIdx.x * wpb + (threadIdx.x >> 6);
    const int nw = gridDim.x * wpb;
    const int lane = threadIdx.x & 63;
    for (int s = wid; s < rows; s += nw) {
        const float4* er = (const float4*)(e + (size_t)s * 768);
        _Float16* dr = dst + (size_t)s * 800;
        float dot = 0.f;
#pragma unroll
        for (int k = 0; k < 3; ++k) {
            const int idx = lane + 64 * k;
            const float4 v = er[idx];
            const float4 w = ((const float4*)w2f)[idx];
            dot += v.x * w.x + v.y * w.y + v.z * w.z + v.w * w.w;
            f16x4 h;
            h[0] = (_Float16)v.x; h[1] = (_Float16)v.y;
            h[2] = (_Float16)v.z; h[3] = (_Float16)v.w;
            *(f16x4*)(dr + 4 * idx) = h;
        }
        for (int o = 32; o; o >>= 1) dot += __shfl_xor(dot, o);
        if (lane < 32) {
            _Float16 v = (_Float16)0.f;
            if (lane == 0) v = (_Float16)1.f;
            if (lane == 1) v = (_Float16)dot;
            dr[768 + lane] = v;
        }
    }
}

__device__ __forceinline__ void gload16(const _Float16* g, _Float16* l) {
    __builtin_amdgcn_global_load_lds(
        (const __attribute__((address_space(1))) unsigned int*)(g),
        (__attribute__((address_space(3))) unsigned int*)(l),
        16, 0, 0);
}

// -------- 128x128 / BK=32 / minimum-2-phase (T3) GEMM, 32 KB LDS -----------
template<bool TANH, bool OUT_F16, bool BIAS, int MODE>
__global__ __launch_bounds__(256)
void gemm_nt_f16(const _Float16* __restrict__ A, const _Float16* __restrict__ Bt,
                 const float* __restrict__ bias, void* __restrict__ Cp,
                 int M, int Nreal, int Nstore, int K,
                 int lda, int ldb, int ldc, int nTileN, int nTiles,
                 long long sA, long long sB, long long sC)
{
    __shared__ __align__(16) _Float16 lds[2 * 8192];   // 2 x (A 4096 + B 4096) hw

    int bid = blockIdx.x;
    int z, tm, tn;
    if (MODE == 0) {
        const int nwg = gridDim.x;
        const int q8 = nwg >> 3, r8 = nwg & 7;
        const int xcd = bid & 7, loc = bid >> 3;
        bid = (xcd < r8 ? xcd * (q8 + 1) : r8 * (q8 + 1) + (xcd - r8) * q8) + loc;
        z = 0;
        tm = bid / nTileN; tn = bid - tm * nTileN;
    } else {
        const int xcd = bid & 7, idx = bid >> 3;
        const int g = idx / nTiles, tile = idx - g * nTiles;
        z = g * 8 + xcd;
        tm = tile / nTileN; tn = tile - tm * nTileN;
    }
    const int m0 = tm << 7, n0 = tn << 7;

    const _Float16* Az = A + (size_t)z * sA;
    const _Float16* Bz = Bt + (size_t)z * sB;

    const int tid = threadIdx.x;
    const int lane = tid & 63;
    const int wid = tid >> 6;
    const int wm = wid >> 1, wn = wid & 1;

    const int r0 = tid >> 2;
    const int c0 = (((tid & 3) ^ ((tid >> 3) & 3)) << 3);
    const int rA0 = (m0 + r0      < M ? m0 + r0      : M - 1);
    const int rA1 = (m0 + r0 + 64 < M ? m0 + r0 + 64 : M - 1);
    const int rB0 = (n0 + r0      < Nreal ? n0 + r0      : Nreal - 1);
    const int rB1 = (n0 + r0 + 64 < Nreal ? n0 + r0 + 64 : Nreal - 1);
    const _Float16* pA0 = Az + (size_t)rA0 * lda + c0;
    const _Float16* pA1 = Az + (size_t)rA1 * lda + c0;
    const _Float16* pB0 = Bz + (size_t)rB0 * ldb + c0;
    const _Float16* pB1 = Bz + (size_t)rB1 * ldb + c0;

    const int o0 = tid * 8, o1 = (tid + 256) * 8;

    const int rr = lane & 15;
    const int hh = lane >> 4;
    const int sw = (rr >> 1) & 3;
    const int fAo = ((wm * 64 + rr) * 4 + (hh ^ sw)) * 8;
    const int fBo = ((wn * 64 + rr) * 4 + (hh ^ sw)) * 8;

    const f32x4 z4 = {0.f, 0.f, 0.f, 0.f};
    f32x4 acc[4][4];
#pragma unroll
    for (int i = 0; i < 4; ++i)
#pragma unroll
        for (int j = 0; j < 4; ++j) acc[i][j] = z4;

    const int nt = K >> 5;

#define STAGE(si, kt)                                              \
    do {                                                           \
        _Float16* base_ = lds + (si) * 8192;                       \
        const int ko_ = (kt) << 5;                                 \
        gload16(pA0 + ko_, base_ + o0);                            \
        gload16(pA1 + ko_, base_ + o1);                            \
        gload16(pB0 + ko_, base_ + 4096 + o0);                     \
        gload16(pB1 + ko_, base_ + 4096 + o1);                     \
    } while (0)

#define COMPUTE(si)                                                            \
    do {                                                                       \
        const _Float16* cA_ = lds + (si) * 8192;                               \
        const _Float16* cB_ = cA_ + 4096;                                      \
        f16x8 a_[4], b_[4];                                                    \
        _Pragma("unroll")                                                      \
        for (int mi = 0; mi < 4; ++mi) a_[mi] = *(const f16x8*)(cA_ + fAo + mi * 512); \
        _Pragma("unroll")                                                      \
        for (int ni = 0; ni < 4; ++ni) b_[ni] = *(const f16x8*)(cB_ + fBo + ni * 512); \
        _Pragma("unroll")                                                      \
        for (int mi = 0; mi < 4; ++mi)                                         \
            _Pragma("unroll")                                                  \
            for (int ni = 0; ni < 4; ++ni)                                     \
                acc[mi][ni] = __builtin_amdgcn_mfma_f32_16x16x32_f16(          \
                    a_[mi], b_[ni], acc[mi][ni], 0, 0, 0);                     \
    } while (0)

    // prologue: tile 0 staged and published
    STAGE(0, 0);
    asm volatile("s_waitcnt vmcnt(0)" ::: "memory");
    __builtin_amdgcn_s_barrier();
    __builtin_amdgcn_sched_barrier(0);

    // T3 minimum-2-phase: stage-first, covered drain at end of iter
    for (int j = 0; j < nt; ++j) {
        if (j + 1 < nt) STAGE((j + 1) & 1, j + 1);
        COMPUTE(j & 1);
        asm volatile("s_waitcnt vmcnt(0)" ::: "memory");
        __builtin_amdgcn_s_barrier();
        __builtin_amdgcn_sched_barrier(0);
    }

#undef STAGE
#undef COMPUTE

    // epilogue: bias -> tanh -> store (zero padded cols [Nreal, Nstore))
    const int cr0 = (lane >> 4) << 2;
    const int cc = lane & 15;
    float*    Cf = (float*)Cp    + (size_t)z * sC;
    _Float16* Ch = (_Float16*)Cp + (size_t)z * sC;
#pragma unroll
    for (int mi = 0; mi < 4; ++mi) {
#pragma unroll
        for (int ni = 0; ni < 4; ++ni) {
            const int gc = n0 + wn * 64 + ni * 16 + cc;
            if (gc >= Nstore) continue;
            const bool real = gc < Nreal;
            float bb = 0.f;
            if (BIAS) bb = real ? bias[gc] : 0.f;
#pragma unroll
            for (int r = 0; r < 4; ++r) {
                const int gr = m0 + wm * 64 + mi * 16 + cr0 + r;
                if (gr >= M) continue;
                float x = real ? (acc[mi][ni][r] + bb) : 0.f;
                if (TANH) x = tanhf(x);
                if (OUT_F16) Ch[(size_t)gr * ldc + gc] = (_Float16)x;
                else         Cf[(size_t)gr * ldc + gc] = x;
            }
        }
    }
}

extern "C" void kernel_launch(void* const* d_in, const int* in_sizes, int n_in,
                              void* d_out, int out_size, void* d_ws, size_t ws_size,
                              hipStream_t stream)
{
    const float* b  = (const float*)d_in[0];
    const float* e  = (const float*)d_in[1];
    const float* Wq = (const float*)d_in[2];
    const float* bq = (const float*)d_in[3];
    const float* Wk = (const float*)d_in[4];
    const float* bk = (const float*)d_in[5];
    const float* Wv = (const float*)d_in[6];
    const float* bv = (const float*)d_in[7];
    float* out = (float*)d_out;

    const int BT = 36928, T = 577, S = 577, Sp = 608, Kb = 800;
    const int Nmg = 1408;   // merged B rows: 800 aug + 608 v-slot

    // ws layout (f16 units): ~212.5 MB total
    _Float16* WqT_h  = (_Float16*)d_ws;                      // 589824
    _Float16* WkT_h  = WqT_h + 589824;                       // 589824
    _Float16* Mt_aug = WkT_h + 589824;                       // 800*768 (B rows 0..799)
    _Float16* Wv_h   = Mt_aug + 614400;                      // 577*768 (B rows 800..1376)
    float*    bias_mg = (float*)(Wv_h + 443136);             // 1408 f32 (2816 hw)
    float*    w2f     = (float*)((_Float16*)bias_mg + 2816); // 768 f32 (1536 hw)
    _Float16* S1    = (_Float16*)w2f + 1536;                 // b_h [BT,768] then e' [BT,800]
    _Float16* S_big = S1 + (size_t)BT * Kb;                  // [BT,1408]
    _Float16* S4    = S_big + (size_t)BT * Nmg;              // attn [BT,608]

    // weight preprocessing
    cvtT2_kernel<<<dim3(24, 24, 2), 256, 0, stream>>>(Wq, WqT_h, Wk, WkT_h);
    cvt8_kernel<<<217, 256, 0, stream>>>(Wv, Wv_h, 55392);
    prep_kernel<<<398, 256, 0, stream>>>(WqT_h, WkT_h, bq, bk, bv, w2f, Mt_aug, bias_mg);
    // Mt = NT(WkT, WqT)  [768x768] -> Mt_aug rows 0..767
    gemm_nt_f16<false, true, false, 0><<<dim3(36, 1, 1), 256, 0, stream>>>(
        WkT_h, WqT_h, nullptr, Mt_aug, 768, 768, 768, 768, 768, 768, 768, 6, 0, 0, 0, 0);

    // b -> f16
    cvt8_kernel<<<2048, 256, 0, stream>>>(b, S1, 3545088);
    // S_big = b_h @ B_merged^T + bias_mg   [BT,1408]  (11 N-tiles, 0 waste)
    gemm_nt_f16<false, true, true, 0><<<dim3(3179, 1, 1), 256, 0, stream>>>(
        S1, Mt_aug, bias_mg, S_big, BT, 1377, Nmg, 768, 768, 768, Nmg, 11, 0, 0, 0, 0);
    // e' (overwrites b_h, dead)
    cvt_e_aug_kernel<<<2048, 256, 0, stream>>>(e, w2f, S1, BT);
    // attn = tanh(NT(S_big[:,0:800], e'))  batched [64][577,608], K=800
    gemm_nt_f16<true, true, false, 1><<<dim3(1600, 1, 1), 256, 0, stream>>>(
        S_big, S1, nullptr, S4, T, S, Sp, Kb, Nmg, Kb, Sp, 5, 25,
        (long long)T * Nmg, (long long)T * Kb, (long long)T * Sp);
    // out = NT(attn, S_big[:,800:1408])  batched [64][577,577] f32, K=608
    gemm_nt_f16<false, false, false, 1><<<dim3(1600, 1, 1), 256, 0, stream>>>(
        S4, S_big + 800, nullptr, out, T, T, T, Sp, Sp, Nmg, T, 5, 25,
        (long long)T * Sp, (long long)T * Nmg, (long long)T * T);
}

// Round 14
// 377.498 us; speedup vs baseline: 1.0424x; 1.0424x over previous
//
#include <hip/hip_runtime.h>
#include <hip/hip_fp16.h>

// Pipeline (all fp16 MFMA, f32 accum):
//   Algebraic fusion (R10): q·k^T = b(Wq^T Wk)e^T + b·w1 + (e·w2) + c0.
//   Merged projection (R11): S_big = b_h @ [Mt|w1|0|Wv]^T + bias  [BT,1408]
//     cols 0..799 = bm' (attn A), cols 800..1407 = v (out B).
//   attn = tanh(NT(S_big[,0:800], e'))  batched ; out = NT(attn, S_big[,800:]).
// Merged GEMM: gemm256 -- m201-class 256x256 / BK=64 / 8 waves / 8-phase:
//   16 slots of 8KB (128 rows x 32 K, XOR-swizzled): A[p][mh][kh], B[p][nh][kh].
//   Iter (tiles t,t+1): 8 phases; each {ds_read frags; 2 slot-stages; barrier;
//   lgkmcnt(0); setprio(1); 16 MFMA (m-pair x 4n x 2kh); setprio(0); barrier}.
//   B-frags register-cached across a tile's 4 phases. Stage schedule:
//   ph0,1: A(t+1); ph2,3: B(t+2); ph4,5: A(t+2); ph6,7: B(t+3).
//   Waits: vmcnt(4) at ph3 (publishes buf1=t+1) and ph7 (publishes buf0=t+2),
//   derived by issue-order counting (4 newer loads outstanding at each point).
//   Slot restage is always >=2 barriers after its last reader. Last iter: ph3
//   uses vmcnt(0), no ph7 wait. nt = K/64 must be even (12 for K=768).
// attn/out/Mt: proven R7 3-stage counted-vmcnt 128x128 kernel (R11 config).
// XOR swizzle (verified R6): chunk c -> row c>>2, col ((c&3)^((c>>3)&3))*8;
// read lane l row r: chunk r*4 + ((l>>4)^((r>>1)&3)). 0 conflicts + coalesced.

typedef _Float16 f16x8 __attribute__((ext_vector_type(8)));
typedef _Float16 f16x4 __attribute__((ext_vector_type(4)));
typedef float f32x4 __attribute__((ext_vector_type(4)));

__global__ void cvt8_kernel(const float* __restrict__ src, _Float16* __restrict__ dst,
                            long long n8) {
    long long i = blockIdx.x * (long long)blockDim.x + threadIdx.x;
    const long long stride = gridDim.x * (long long)blockDim.x;
    for (; i < n8; i += stride) {
        const float4 f0 = ((const float4*)src)[2 * i];
        const float4 f1 = ((const float4*)src)[2 * i + 1];
        f16x8 h;
        h[0] = (_Float16)f0.x; h[1] = (_Float16)f0.y; h[2] = (_Float16)f0.z; h[3] = (_Float16)f0.w;
        h[4] = (_Float16)f1.x; h[5] = (_Float16)f1.y; h[6] = (_Float16)f1.z; h[7] = (_Float16)f1.w;
        ((f16x8*)dst)[i] = h;
    }
}

__global__ void cvtT2_kernel(const float* __restrict__ s0, _Float16* __restrict__ d0,
                             const float* __restrict__ s1, _Float16* __restrict__ d1) {
    __shared__ float t[32][33];
    const float* src = blockIdx.z ? s1 : s0;
    _Float16* dst = blockIdx.z ? d1 : d0;
    const int bx = blockIdx.x, by = blockIdx.y;
    const int tx = threadIdx.x & 31, ty = threadIdx.x >> 5;
#pragma unroll
    for (int k = 0; k < 4; ++k) {
        const int r = ty + 8 * k;
        t[r][tx] = src[(size_t)(by * 32 + r) * 768 + bx * 32 + tx];
    }
    __syncthreads();
#pragma unroll
    for (int k = 0; k < 4; ++k) {
        const int r = ty + 8 * k;
        dst[(size_t)(bx * 32 + r) * 768 + by * 32 + tx] = (_Float16)t[tx][r];
    }
}

__global__ void prep_kernel(const _Float16* __restrict__ WqT, const _Float16* __restrict__ WkT,
                            const float* __restrict__ bq, const float* __restrict__ bk,
                            const float* __restrict__ bv,
                            float* __restrict__ w2f, _Float16* __restrict__ Mt_aug,
                            float* __restrict__ bias_mg) {
    const int wid = blockIdx.x * 4 + (threadIdx.x >> 6);
    const int lane = threadIdx.x & 63;
    if (wid < 768) {
        float s = 0.f;
        for (int k = 0; k < 12; ++k) s += (float)WqT[(size_t)wid * 768 + lane + 64 * k] * bk[lane + 64 * k];
        for (int o = 32; o; o >>= 1) s += __shfl_xor(s, o);
        if (lane == 0) Mt_aug[(size_t)768 * 768 + wid] = (_Float16)s;
    } else if (wid < 1536) {
        const int n = wid - 768;
        float s = 0.f;
        for (int k = 0; k < 12; ++k) s += (float)WkT[(size_t)n * 768 + lane + 64 * k] * bq[lane + 64 * k];
        for (int o = 32; o; o >>= 1) s += __shfl_xor(s, o);
        if (lane == 0) w2f[n] = s;
    } else if (wid == 1536) {
        float s = 0.f;
        for (int k = 0; k < 12; ++k) s += bq[lane + 64 * k] * bk[lane + 64 * k];
        for (int o = 32; o; o >>= 1) s += __shfl_xor(s, o);
        if (lane < 32) {
            float v = 0.f;
            if (lane == 0) v = s;
            if (lane == 1) v = 1.f;
            bias_mg[768 + lane] = v;
        }
    } else if (wid < 1560) {
        const int i = (wid - 1537) * 64 + lane;
        if (i < 768) bias_mg[i] = 0.f;
        else {
            const int j = i + 32;
            if (j < 1408) bias_mg[j] = (j < 1377) ? bv[j - 800] : 0.f;
        }
    } else if (wid < 1591) {
        const int r = 769 + (wid - 1560);
        for (int k = 0; k < 12; ++k) Mt_aug[(size_t)r * 768 + lane + 64 * k] = (_Float16)0.f;
    }
}

__global__ void cvt_e_aug_kernel(const float* __restrict__ e, const float* __restrict__ w2f,
                                 _Float16* __restrict__ dst, int rows) {
    const int wpb = blockDim.x >> 6;
    int wid = blockIdx.x * wpb + (threadIdx.x >> 6);
    const int nw = gridDim.x * wpb;
    const int lane = threadIdx.x & 63;
    for (int s = wid; s < rows; s += nw) {
        const float4* er = (const float4*)(e + (size_t)s * 768);
        _Float16* dr = dst + (size_t)s * 800;
        float dot = 0.f;
#pragma unroll
        for (int k = 0; k < 3; ++k) {
            const int idx = lane + 64 * k;
            const float4 v = er[idx];
            const float4 w = ((const float4*)w2f)[idx];
            dot += v.x * w.x + v.y * w.y + v.z * w.z + v.w * w.w;
            f16x4 h;
            h[0] = (_Float16)v.x; h[1] = (_Float16)v.y;
            h[2] = (_Float16)v.z; h[3] = (_Float16)v.w;
            *(f16x4*)(dr + 4 * idx) = h;
        }
        for (int o = 32; o; o >>= 1) dot += __shfl_xor(dot, o);
        if (lane < 32) {
            _Float16 v = (_Float16)0.f;
            if (lane == 0) v = (_Float16)1.f;
            if (lane == 1) v = (_Float16)dot;
            dr[768 + lane] = v;
        }
    }
}

__device__ __forceinline__ void gload16(const _Float16* g, _Float16* l) {
    __builtin_amdgcn_global_load_lds(
        (const __attribute__((address_space(1))) unsigned int*)(g),
        (__attribute__((address_space(3))) unsigned int*)(l),
        16, 0, 0);
}

// ============ gemm256: 256x256 / BK=64 / 8-wave 8-phase (merged GEMM) =======
__global__ __launch_bounds__(512, 2)
void gemm256(const _Float16* __restrict__ A, const _Float16* __restrict__ Bt,
             const float* __restrict__ bias, _Float16* __restrict__ C,
             int M, int Nreal, int Nstore, int K,
             int lda, int ldb, int ldc, int nTileN)
{
    __shared__ __align__(16) _Float16 lds[65536];   // 128 KiB = 16 x 8KB slots

    int bid = blockIdx.x;
    {   // bijective XCD chunking (m204)
        const int nwg = gridDim.x;
        const int q8 = nwg >> 3, r8 = nwg & 7;
        const int xcd = bid & 7, loc = bid >> 3;
        bid = (xcd < r8 ? xcd * (q8 + 1) : r8 * (q8 + 1) + (xcd - r8) * q8) + loc;
    }
    const int tm = bid / nTileN, tn = bid - tm * nTileN;
    const int m0 = tm << 8, n0 = tn << 8;

    const int tid = threadIdx.x;
    const int lane = tid & 63;
    const int wid = tid >> 6;
    const int wm = wid >> 2;            // 0..1 M-half (128 rows)
    const int wn = wid & 3;             // 0..3 N-quarter (64 cols)
    const int nhB = wn >> 1;            // B slot half

    // staging: thread owns chunk tid of each slot; row tid>>2, swizzled col
    const int srow = tid >> 2;          // 0..127
    const int scol = (((tid & 3) ^ ((tid >> 3) & 3)) << 3);
    int ra0 = m0 + srow;        if (ra0 >= M) ra0 = M - 1;
    int ra1 = m0 + 128 + srow;  if (ra1 >= M) ra1 = M - 1;
    int rb0 = n0 + srow;        if (rb0 >= Nreal) rb0 = Nreal - 1;
    int rb1 = n0 + 128 + srow;  if (rb1 >= Nreal) rb1 = Nreal - 1;
    const _Float16* pA[2] = { A + (size_t)ra0 * lda + scol, A + (size_t)ra1 * lda + scol };
    const _Float16* pB[2] = { Bt + (size_t)rb0 * ldb + scol, Bt + (size_t)rb1 * ldb + scol };

    // fragment read offsets (hw) within a slot
    const int rr = lane & 15;
    const int hh = lane >> 4;
    const int sw = (rr >> 1) & 3;
    const int fA0 = (rr * 4 + (hh ^ sw)) * 8;          // + mi*512
    const int fB0 = (wn & 1) * 2048 + fA0;             // + nj*512

#define SA(p, mh, kh, kt) \
    gload16(pA[mh] + ((kt) << 6) + ((kh) << 5), lds + ((p) * 4 + (mh) * 2 + (kh)) * 4096 + tid * 8)
#define SB(p, nh, kh, kt) \
    gload16(pB[nh] + ((kt) << 6) + ((kh) << 5), lds + 32768 + ((p) * 4 + (nh) * 2 + (kh)) * 4096 + tid * 8)
#define RA(p, kh, mi) (*(const f16x8*)(lds + ((p) * 4 + wm * 2 + (kh)) * 4096 + fA0 + (mi) * 512))
#define RB(p, kh, nj) (*(const f16x8*)(lds + 32768 + ((p) * 4 + nhB * 2 + (kh)) * 4096 + fB0 + (nj) * 512))

    const f32x4 z4 = {0.f, 0.f, 0.f, 0.f};
    f32x4 acc[8][4];
#pragma unroll
    for (int i = 0; i < 8; ++i)
#pragma unroll
        for (int j = 0; j < 4; ++j) acc[i][j] = z4;

    const int nt = K >> 6;              // 12 (even)

    // MFMA cluster for m-pair mq of buf p (a-frags given)
#define MMA(mq, a00, a01, a10, a11)                                                  \
    do {                                                                             \
        _Pragma("unroll")                                                            \
        for (int nj = 0; nj < 4; ++nj) {                                             \
            acc[2*(mq)][nj]   = __builtin_amdgcn_mfma_f32_16x16x32_f16(a00, bf[nj][0], acc[2*(mq)][nj], 0, 0, 0);   \
            acc[2*(mq)][nj]   = __builtin_amdgcn_mfma_f32_16x16x32_f16(a01, bf[nj][1], acc[2*(mq)][nj], 0, 0, 0);   \
            acc[2*(mq)+1][nj] = __builtin_amdgcn_mfma_f32_16x16x32_f16(a10, bf[nj][0], acc[2*(mq)+1][nj], 0, 0, 0); \
            acc[2*(mq)+1][nj] = __builtin_amdgcn_mfma_f32_16x16x32_f16(a11, bf[nj][1], acc[2*(mq)+1][nj], 0, 0, 0); \
        }                                                                            \
    } while (0)

    // one phase: ds_reads, optional B-frag refill, stage ops, optional wait,
    // barrier, lgkm drain, prio-wrapped MFMA, barrier.
#define PHASE(p, mq, BLOAD, STAGEOPS, WAITOP)                                        \
    do {                                                                             \
        f16x8 a00 = RA(p, 0, 2*(mq)),   a01 = RA(p, 1, 2*(mq));                      \
        f16x8 a10 = RA(p, 0, 2*(mq)+1), a11 = RA(p, 1, 2*(mq)+1);                    \
        if (BLOAD) {                                                                 \
            _Pragma("unroll")                                                        \
            for (int nj = 0; nj < 4; ++nj) {                                         \
                bf[nj][0] = RB(p, 0, nj);                                            \
                bf[nj][1] = RB(p, 1, nj);                                            \
            }                                                                        \
        }                                                                            \
        STAGEOPS;                                                                    \
        WAITOP;                                                                      \
        __builtin_amdgcn_s_barrier();                                                \
        asm volatile("s_waitcnt lgkmcnt(0)" ::: "memory");                           \
        __builtin_amdgcn_sched_barrier(0);                                           \
        __builtin_amdgcn_s_setprio(1);                                               \
        MMA(mq, a00, a01, a10, a11);                                                 \
        __builtin_amdgcn_s_setprio(0);                                               \
        __builtin_amdgcn_s_barrier();                                                \
    } while (0)

    // prologue: tile0 full (8) + tile1 B (4); retire tile0 (keep 4 in flight)
    SA(0,0,0,0); SA(0,0,1,0); SA(0,1,0,0); SA(0,1,1,0);
    SB(0,0,0,0); SB(0,0,1,0); SB(0,1,0,0); SB(0,1,1,0);
    SB(1,0,0,1); SB(1,0,1,1); SB(1,1,0,1); SB(1,1,1,1);
    asm volatile("s_waitcnt vmcnt(4)" ::: "memory");
    __builtin_amdgcn_s_barrier();

    f16x8 bf[4][2];
    for (int t = 0; t < nt; t += 2) {
        const bool more = (t + 2 < nt);
        // tile t (buf0)
        PHASE(0, 0, true,  { SA(1,0,0,t+1); SA(1,0,1,t+1); }, );
        PHASE(0, 1, false, { SA(1,1,0,t+1); SA(1,1,1,t+1); }, );
        PHASE(0, 2, false, { if (more) { SB(0,0,0,t+2); SB(0,0,1,t+2); } }, );
        PHASE(0, 3, false, { if (more) { SB(0,1,0,t+2); SB(0,1,1,t+2); } },
              { if (more) asm volatile("s_waitcnt vmcnt(4)" ::: "memory");
                else      asm volatile("s_waitcnt vmcnt(0)" ::: "memory"); });
        // tile t+1 (buf1)
        PHASE(1, 0, true,  { if (more) { SA(0,0,0,t+2); SA(0,0,1,t+2); } }, );
        PHASE(1, 1, false, { if (more) { SA(0,1,0,t+2); SA(0,1,1,t+2); } }, );
        PHASE(1, 2, false, { if (more) { SB(1,0,0,t+3); SB(1,0,1,t+3); } }, );
        PHASE(1, 3, false, { if (more) { SB(1,1,0,t+3); SB(1,1,1,t+3); } },
              { if (more) asm volatile("s_waitcnt vmcnt(4)" ::: "memory"); });
    }

#undef SA
#undef SB
#undef RA
#undef RB
#undef MMA
#undef PHASE

    // epilogue: bias -> f16 store (zero cols [Nreal, Nstore); skip >= Nstore)
    const int cr0 = (lane >> 4) << 2;
    const int cc = lane & 15;
#pragma unroll
    for (int mi = 0; mi < 8; ++mi) {
#pragma unroll
        for (int nj = 0; nj < 4; ++nj) {
            const int gc = n0 + wn * 64 + nj * 16 + cc;
            if (gc >= Nstore) continue;
            const bool real = gc < Nreal;
            const float bb = real ? bias[gc] : 0.f;
#pragma unroll
            for (int r = 0; r < 4; ++r) {
                const int gr = m0 + wm * 128 + mi * 16 + cr0 + r;
                if (gr >= M) continue;
                const float x = real ? (acc[mi][nj][r] + bb) : 0.f;
                C[(size_t)gr * ldc + gc] = (_Float16)x;
            }
        }
    }
}

// -------- gemm_nt_f16: 128x128 / BK=32 / 3-stage counted-vmcnt (R7) ---------
template<bool TANH, bool OUT_F16, bool BIAS, int MODE>
__global__ __launch_bounds__(256)
void gemm_nt_f16(const _Float16* __restrict__ A, const _Float16* __restrict__ Bt,
                 const float* __restrict__ bias, void* __restrict__ Cp,
                 int M, int Nreal, int Nstore, int K,
                 int lda, int ldb, int ldc, int nTileN, int nTiles,
                 long long sA, long long sB, long long sC)
{
    __shared__ __align__(16) _Float16 lds[3 * 8192];

    int bid = blockIdx.x;
    int z, tm, tn;
    if (MODE == 0) {
        const int nwg = gridDim.x;
        const int q8 = nwg >> 3, r8 = nwg & 7;
        const int xcd = bid & 7, loc = bid >> 3;
        bid = (xcd < r8 ? xcd * (q8 + 1) : r8 * (q8 + 1) + (xcd - r8) * q8) + loc;
        z = 0;
        tm = bid / nTileN; tn = bid - tm * nTileN;
    } else {
        const int xcd = bid & 7, idx = bid >> 3;
        const int g = idx / nTiles, tile = idx - g * nTiles;
        z = g * 8 + xcd;
        tm = tile / nTileN; tn = tile - tm * nTileN;
    }
    const int m0 = tm << 7, n0 = tn << 7;

    const _Float16* Az = A + (size_t)z * sA;
    const _Float16* Bz = Bt + (size_t)z * sB;

    const int tid = threadIdx.x;
    const int lane = tid & 63;
    const int wid = tid >> 6;
    const int wm = wid >> 1, wn = wid & 1;

    const int r0 = tid >> 2;
    const int c0 = (((tid & 3) ^ ((tid >> 3) & 3)) << 3);
    const int rA0 = (m0 + r0      < M ? m0 + r0      : M - 1);
    const int rA1 = (m0 + r0 + 64 < M ? m0 + r0 + 64 : M - 1);
    const int rB0 = (n0 + r0      < Nreal ? n0 + r0      : Nreal - 1);
    const int rB1 = (n0 + r0 + 64 < Nreal ? n0 + r0 + 64 : Nreal - 1);
    const _Float16* pA0 = Az + (size_t)rA0 * lda + c0;
    const _Float16* pA1 = Az + (size_t)rA1 * lda + c0;
    const _Float16* pB0 = Bz + (size_t)rB0 * ldb + c0;
    const _Float16* pB1 = Bz + (size_t)rB1 * ldb + c0;

    const int o0 = tid * 8, o1 = (tid + 256) * 8;

    const int rr = lane & 15;
    const int hh = lane >> 4;
    const int sw = (rr >> 1) & 3;
    const int fAo = ((wm * 64 + rr) * 4 + (hh ^ sw)) * 8;
    const int fBo = ((wn * 64 + rr) * 4 + (hh ^ sw)) * 8;

    const f32x4 z4 = {0.f, 0.f, 0.f, 0.f};
    f32x4 acc[4][4];
#pragma unroll
    for (int i = 0; i < 4; ++i)
#pragma unroll
        for (int j = 0; j < 4; ++j) acc[i][j] = z4;

    const int nt = K >> 5;

#define STAGE(si, kt)                                              \
    do {                                                           \
        _Float16* base_ = lds + (si) * 8192;                       \
        const int ko_ = (kt) << 5;                                 \
        gload16(pA0 + ko_, base_ + o0);                            \
        gload16(pA1 + ko_, base_ + o1);                            \
        gload16(pB0 + ko_, base_ + 4096 + o0);                     \
        gload16(pB1 + ko_, base_ + 4096 + o1);                     \
    } while (0)

#define COMPUTE(si)                                                            \
    do {                                                                       \
        const _Float16* cA_ = lds + (si) * 8192;                               \
        const _Float16* cB_ = cA_ + 4096;                                      \
        f16x8 a_[4], b_[4];                                                    \
        _Pragma("unroll")                                                      \
        for (int mi = 0; mi < 4; ++mi) a_[mi] = *(const f16x8*)(cA_ + fAo + mi * 512); \
        _Pragma("unroll")                                                      \
        for (int ni = 0; ni < 4; ++ni) b_[ni] = *(const f16x8*)(cB_ + fBo + ni * 512); \
        _Pragma("unroll")                                                      \
        for (int mi = 0; mi < 4; ++mi)                                         \
            _Pragma("unroll")                                                  \
            for (int ni = 0; ni < 4; ++ni)                                     \
                acc[mi][ni] = __builtin_amdgcn_mfma_f32_16x16x32_f16(          \
                    a_[mi], b_[ni], acc[mi][ni], 0, 0, 0);                     \
    } while (0)

    STAGE(0, 0);
    STAGE(1, 1);

    for (int j = 0; j < nt - 1; ++j) {
        asm volatile("s_waitcnt vmcnt(4)" ::: "memory");
        __builtin_amdgcn_s_barrier();
        __builtin_amdgcn_sched_barrier(0);
        if (j + 2 < nt) STAGE((j + 2) % 3, j + 2);
        COMPUTE(j % 3);
    }
    asm volatile("s_waitcnt vmcnt(0)" ::: "memory");
    __builtin_amdgcn_s_barrier();
    __builtin_amdgcn_sched_barrier(0);
    COMPUTE((nt - 1) % 3);

#undef STAGE
#undef COMPUTE

    const int cr0 = (lane >> 4) << 2;
    const int cc = lane & 15;
    float*    Cf = (float*)Cp    + (size_t)z * sC;
    _Float16* Ch = (_Float16*)Cp + (size_t)z * sC;
#pragma unroll
    for (int mi = 0; mi < 4; ++mi) {
#pragma unroll
        for (int ni = 0; ni < 4; ++ni) {
            const int gc = n0 + wn * 64 + ni * 16 + cc;
            if (gc >= Nstore) continue;
            const bool real = gc < Nreal;
            float bb = 0.f;
            if (BIAS) bb = real ? bias[gc] : 0.f;
#pragma unroll
            for (int r = 0; r < 4; ++r) {
                const int gr = m0 + wm * 64 + mi * 16 + cr0 + r;
                if (gr >= M) continue;
                float x = real ? (acc[mi][ni][r] + bb) : 0.f;
                if (TANH) x = tanhf(x);
                if (OUT_F16) Ch[(size_t)gr * ldc + gc] = (_Float16)x;
                else         Cf[(size_t)gr * ldc + gc] = x;
            }
        }
    }
}

extern "C" void kernel_launch(void* const* d_in, const int* in_sizes, int n_in,
                              void* d_out, int out_size, void* d_ws, size_t ws_size,
                              hipStream_t stream)
{
    const float* b  = (const float*)d_in[0];
    const float* e  = (const float*)d_in[1];
    const float* Wq = (const float*)d_in[2];
    const float* bq = (const float*)d_in[3];
    const float* Wk = (const float*)d_in[4];
    const float* bk = (const float*)d_in[5];
    const float* Wv = (const float*)d_in[6];
    const float* bv = (const float*)d_in[7];
    float* out = (float*)d_out;

    const int BT = 36928, T = 577, S = 577, Sp = 608, Kb = 800;
    const int Nmg = 1408;   // merged B rows: 800 aug + 608 v-slot

    // ws layout (f16 units): ~212.5 MB total
    _Float16* WqT_h  = (_Float16*)d_ws;                      // 589824
    _Float16* WkT_h  = WqT_h + 589824;                       // 589824
    _Float16* Mt_aug = WkT_h + 589824;                       // 800*768 (B rows 0..799)
    _Float16* Wv_h   = Mt_aug + 614400;                      // 577*768 (B rows 800..1376)
    float*    bias_mg = (float*)(Wv_h + 443136);             // 1408 f32 (2816 hw)
    float*    w2f     = (float*)((_Float16*)bias_mg + 2816); // 768 f32 (1536 hw)
    _Float16* S1    = (_Float16*)w2f + 1536;                 // b_h [BT,768] then e' [BT,800]
    _Float16* S_big = S1 + (size_t)BT * Kb;                  // [BT,1408]
    _Float16* S4    = S_big + (size_t)BT * Nmg;              // attn [BT,608]

    // weight preprocessing
    cvtT2_kernel<<<dim3(24, 24, 2), 256, 0, stream>>>(Wq, WqT_h, Wk, WkT_h);
    cvt8_kernel<<<217, 256, 0, stream>>>(Wv, Wv_h, 55392);
    prep_kernel<<<398, 256, 0, stream>>>(WqT_h, WkT_h, bq, bk, bv, w2f, Mt_aug, bias_mg);
    // Mt = NT(WkT, WqT)  [768x768] -> Mt_aug rows 0..767
    gemm_nt_f16<false, true, false, 0><<<dim3(36, 1, 1), 256, 0, stream>>>(
        WkT_h, WqT_h, nullptr, Mt_aug, 768, 768, 768, 768, 768, 768, 768, 6, 0, 0, 0, 0);

    // b -> f16
    cvt8_kernel<<<2048, 256, 0, stream>>>(b, S1, 3545088);
    // S_big = b_h @ B_merged^T + bias_mg   [BT,1408]  (145 x 6 tiles of 256^2)
    gemm256<<<dim3(870, 1, 1), 512, 0, stream>>>(
        S1, Mt_aug, bias_mg, S_big, BT, 1377, Nmg, 768, 768, 768, Nmg, 6);
    // e' (overwrites b_h, dead)
    cvt_e_aug_kernel<<<2048, 256, 0, stream>>>(e, w2f, S1, BT);
    // attn = tanh(NT(S_big[:,0:800], e'))  batched [64][577,608], K=800
    gemm_nt_f16<true, true, false, 1><<<dim3(1600, 1, 1), 256, 0, stream>>>(
        S_big, S1, nullptr, S4, T, S, Sp, Kb, Nmg, Kb, Sp, 5, 25,
        (long long)T * Nmg, (long long)T * Kb, (long long)T * Sp);
    // out = NT(attn, S_big[:,800:1408])  batched [64][577,577] f32, K=608
    gemm_nt_f16<false, false, false, 1><<<dim3(1600, 1, 1), 256, 0, stream>>>(
        S4, S_big + 800, nullptr, out, T, T, T, Sp, Sp, Nmg, T, 5, 25,
        (long long)T * Sp, (long long)T * Nmg, (long long)T * T);
}

// Round 15
// 346.044 us; speedup vs baseline: 1.1371x; 1.0909x over previous
//
#include <hip/hip_runtime.h>
#include <hip/hip_fp16.h>

// Pipeline (all fp16 MFMA, f32 accum), R7-proven 3-stage GEMM structure:
//   Algebraic fusion (R10): q·k^T = b(Wq^T Wk)e^T + b·w1 + (e·w2) + c0.
//   Merged projection (R11): S_big = b_h @ [Mt|w1|0|Wv]^T + bias  [BT,1408]
//     cols 0..799 = bm' (attn A), cols 800..1407 = v (out B).
//   attn = tanh(NT(S_big[,0:800], e'))  batched ; out = NT(attn, S_big[,800:]).
// R15: fast tanh in the attn epilogue -- tanh(x) = 1 - 2*rcp(exp2(2log2e*x)+1)
//   (v_exp_f32 + v_rcp_f32, overflow-safe at both ends; ~4 ops vs libm ~20).
// GEMMs: NT, 128x128 tile, BK=32, 3-stage counted-vmcnt pipeline (R7),
// XOR-swizzled LDS (0 bank conflicts + coalesced gload_lds writes),
// MODE0 = bijective XCD chunking; MODE1 = batch->XCD co-location.
// NOTE (R8/R12/R13/R14 lessons): K=768 is too shallow for 8-phase/256^2 or
// BK=64 schedules -- occupancy-rich 3-stage 128^2 is the right structure here.

typedef _Float16 f16x8 __attribute__((ext_vector_type(8)));
typedef _Float16 f16x4 __attribute__((ext_vector_type(4)));
typedef float f32x4 __attribute__((ext_vector_type(4)));

__global__ void cvt8_kernel(const float* __restrict__ src, _Float16* __restrict__ dst,
                            long long n8) {
    long long i = blockIdx.x * (long long)blockDim.x + threadIdx.x;
    const long long stride = gridDim.x * (long long)blockDim.x;
    for (; i < n8; i += stride) {
        const float4 f0 = ((const float4*)src)[2 * i];
        const float4 f1 = ((const float4*)src)[2 * i + 1];
        f16x8 h;
        h[0] = (_Float16)f0.x; h[1] = (_Float16)f0.y; h[2] = (_Float16)f0.z; h[3] = (_Float16)f0.w;
        h[4] = (_Float16)f1.x; h[5] = (_Float16)f1.y; h[6] = (_Float16)f1.z; h[7] = (_Float16)f1.w;
        ((f16x8*)dst)[i] = h;
    }
}

// two f32 [768,768] -> f16 transposed [768,768] (z selects matrix)
__global__ void cvtT2_kernel(const float* __restrict__ s0, _Float16* __restrict__ d0,
                             const float* __restrict__ s1, _Float16* __restrict__ d1) {
    __shared__ float t[32][33];
    const float* src = blockIdx.z ? s1 : s0;
    _Float16* dst = blockIdx.z ? d1 : d0;
    const int bx = blockIdx.x, by = blockIdx.y;
    const int tx = threadIdx.x & 31, ty = threadIdx.x >> 5;
#pragma unroll
    for (int k = 0; k < 4; ++k) {
        const int r = ty + 8 * k;
        t[r][tx] = src[(size_t)(by * 32 + r) * 768 + bx * 32 + tx];
    }
    __syncthreads();
#pragma unroll
    for (int k = 0; k < 4; ++k) {
        const int r = ty + 8 * k;
        dst[(size_t)(bx * 32 + r) * 768 + by * 32 + tx] = (_Float16)t[tx][r];
    }
}

// w1 -> Mt_aug row 768 ; w2f ; bias_mg[1408] ; zero Mt_aug rows 769..799
__global__ void prep_kernel(const _Float16* __restrict__ WqT, const _Float16* __restrict__ WkT,
                            const float* __restrict__ bq, const float* __restrict__ bk,
                            const float* __restrict__ bv,
                            float* __restrict__ w2f, _Float16* __restrict__ Mt_aug,
                            float* __restrict__ bias_mg) {
    const int wid = blockIdx.x * 4 + (threadIdx.x >> 6);
    const int lane = threadIdx.x & 63;
    if (wid < 768) {                 // w1[wid] = WqT[wid,:]·bk
        float s = 0.f;
        for (int k = 0; k < 12; ++k) s += (float)WqT[(size_t)wid * 768 + lane + 64 * k] * bk[lane + 64 * k];
        for (int o = 32; o; o >>= 1) s += __shfl_xor(s, o);
        if (lane == 0) Mt_aug[(size_t)768 * 768 + wid] = (_Float16)s;
    } else if (wid < 1536) {         // w2[n] = WkT[n,:]·bq
        const int n = wid - 768;
        float s = 0.f;
        for (int k = 0; k < 12; ++k) s += (float)WkT[(size_t)n * 768 + lane + 64 * k] * bq[lane + 64 * k];
        for (int o = 32; o; o >>= 1) s += __shfl_xor(s, o);
        if (lane == 0) w2f[n] = s;
    } else if (wid == 1536) {        // c0 -> bias_mg[768], 1 -> [769], 0 -> 770..799
        float s = 0.f;
        for (int k = 0; k < 12; ++k) s += bq[lane + 64 * k] * bk[lane + 64 * k];
        for (int o = 32; o; o >>= 1) s += __shfl_xor(s, o);
        if (lane < 32) {
            float v = 0.f;
            if (lane == 0) v = s;
            if (lane == 1) v = 1.f;
            bias_mg[768 + lane] = v;
        }
    } else if (wid < 1560) {         // bias_mg: zeros 0..767 ; bv -> 800..1376 ; 0 pads
        const int i = (wid - 1537) * 64 + lane;     // [0,1472)
        if (i < 768) bias_mg[i] = 0.f;
        else {
            const int j = i + 32;                   // 800..1503
            if (j < 1408) bias_mg[j] = (j < 1377) ? bv[j - 800] : 0.f;
        }
    } else if (wid < 1591) {         // zero Mt_aug rows 769..799
        const int r = 769 + (wid - 1560);
        for (int k = 0; k < 12; ++k) Mt_aug[(size_t)r * 768 + lane + 64 * k] = (_Float16)0.f;
    }
}

// e f32 [rows,768] -> e' f16 [rows,800]: cvt + col768=1 + col769=e·w2 + 770..799=0
__global__ void cvt_e_aug_kernel(const float* __restrict__ e, const float* __restrict__ w2f,
                                 _Float16* __restrict__ dst, int rows) {
    const int wpb = blockDim.x >> 6;
    int wid = blockIdx.x * wpb + (threadIdx.x >> 6);
    const int nw = gridDim.x * wpb;
    const int lane = threadIdx.x & 63;
    for (int s = wid; s < rows; s += nw) {
        const float4* er = (const float4*)(e + (size_t)s * 768);
        _Float16* dr = dst + (size_t)s * 800;
        float dot = 0.f;
#pragma unroll
        for (int k = 0; k < 3; ++k) {
            const int idx = lane + 64 * k;
            const float4 v = er[idx];
            const float4 w = ((const float4*)w2f)[idx];
            dot += v.x * w.x + v.y * w.y + v.z * w.z + v.w * w.w;
            f16x4 h;
            h[0] = (_Float16)v.x; h[1] = (_Float16)v.y;
            h[2] = (_Float16)v.z; h[3] = (_Float16)v.w;
            *(f16x4*)(dr + 4 * idx) = h;
        }
        for (int o = 32; o; o >>= 1) dot += __shfl_xor(dot, o);
        if (lane < 32) {
            _Float16 v = (_Float16)0.f;
            if (lane == 0) v = (_Float16)1.f;
            if (lane == 1) v = (_Float16)dot;
            dr[768 + lane] = v;
        }
    }
}

__device__ __forceinline__ void gload16(const _Float16* g, _Float16* l) {
    __builtin_amdgcn_global_load_lds(
        (const __attribute__((address_space(1))) unsigned int*)(g),
        (__attribute__((address_space(3))) unsigned int*)(l),
        16, 0, 0);
}

// overflow-safe fast tanh: 1 - 2*rcp(exp2(2log2e*x)+1)
__device__ __forceinline__ float fast_tanh(float x) {
    const float t = __builtin_amdgcn_exp2f(2.885390081777927f * x);
    return 1.f - 2.f * __builtin_amdgcn_rcpf(t + 1.f);
}

// -------- 128x128 / BK=32 / 3-stage counted-vmcnt GEMM (R7, proven) ----------
template<bool TANH, bool OUT_F16, bool BIAS, int MODE>
__global__ __launch_bounds__(256)
void gemm_nt_f16(const _Float16* __restrict__ A, const _Float16* __restrict__ Bt,
                 const float* __restrict__ bias, void* __restrict__ Cp,
                 int M, int Nreal, int Nstore, int K,
                 int lda, int ldb, int ldc, int nTileN, int nTiles,
                 long long sA, long long sB, long long sC)
{
    __shared__ __align__(16) _Float16 lds[3 * 8192];

    int bid = blockIdx.x;
    int z, tm, tn;
    if (MODE == 0) {
        const int nwg = gridDim.x;
        const int q8 = nwg >> 3, r8 = nwg & 7;
        const int xcd = bid & 7, loc = bid >> 3;
        bid = (xcd < r8 ? xcd * (q8 + 1) : r8 * (q8 + 1) + (xcd - r8) * q8) + loc;
        z = 0;
        tm = bid / nTileN; tn = bid - tm * nTileN;
    } else {
        const int xcd = bid & 7, idx = bid >> 3;
        const int g = idx / nTiles, tile = idx - g * nTiles;
        z = g * 8 + xcd;
        tm = tile / nTileN; tn = tile - tm * nTileN;
    }
    const int m0 = tm << 7, n0 = tn << 7;

    const _Float16* Az = A + (size_t)z * sA;
    const _Float16* Bz = Bt + (size_t)z * sB;

    const int tid = threadIdx.x;
    const int lane = tid & 63;
    const int wid = tid >> 6;
    const int wm = wid >> 1, wn = wid & 1;

    const int r0 = tid >> 2;
    const int c0 = (((tid & 3) ^ ((tid >> 3) & 3)) << 3);
    const int rA0 = (m0 + r0      < M ? m0 + r0      : M - 1);
    const int rA1 = (m0 + r0 + 64 < M ? m0 + r0 + 64 : M - 1);
    const int rB0 = (n0 + r0      < Nreal ? n0 + r0      : Nreal - 1);
    const int rB1 = (n0 + r0 + 64 < Nreal ? n0 + r0 + 64 : Nreal - 1);
    const _Float16* pA0 = Az + (size_t)rA0 * lda + c0;
    const _Float16* pA1 = Az + (size_t)rA1 * lda + c0;
    const _Float16* pB0 = Bz + (size_t)rB0 * ldb + c0;
    const _Float16* pB1 = Bz + (size_t)rB1 * ldb + c0;

    const int o0 = tid * 8, o1 = (tid + 256) * 8;

    const int rr = lane & 15;
    const int hh = lane >> 4;
    const int sw = (rr >> 1) & 3;
    const int fAo = ((wm * 64 + rr) * 4 + (hh ^ sw)) * 8;
    const int fBo = ((wn * 64 + rr) * 4 + (hh ^ sw)) * 8;

    const f32x4 z4 = {0.f, 0.f, 0.f, 0.f};
    f32x4 acc[4][4];
#pragma unroll
    for (int i = 0; i < 4; ++i)
#pragma unroll
        for (int j = 0; j < 4; ++j) acc[i][j] = z4;

    const int nt = K >> 5;

#define STAGE(si, kt)                                              \
    do {                                                           \
        _Float16* base_ = lds + (si) * 8192;                       \
        const int ko_ = (kt) << 5;                                 \
        gload16(pA0 + ko_, base_ + o0);                            \
        gload16(pA1 + ko_, base_ + o1);                            \
        gload16(pB0 + ko_, base_ + 4096 + o0);                     \
        gload16(pB1 + ko_, base_ + 4096 + o1);                     \
    } while (0)

#define COMPUTE(si)                                                            \
    do {                                                                       \
        const _Float16* cA_ = lds + (si) * 8192;                               \
        const _Float16* cB_ = cA_ + 4096;                                      \
        f16x8 a_[4], b_[4];                                                    \
        _Pragma("unroll")                                                      \
        for (int mi = 0; mi < 4; ++mi) a_[mi] = *(const f16x8*)(cA_ + fAo + mi * 512); \
        _Pragma("unroll")                                                      \
        for (int ni = 0; ni < 4; ++ni) b_[ni] = *(const f16x8*)(cB_ + fBo + ni * 512); \
        _Pragma("unroll")                                                      \
        for (int mi = 0; mi < 4; ++mi)                                         \
            _Pragma("unroll")                                                  \
            for (int ni = 0; ni < 4; ++ni)                                     \
                acc[mi][ni] = __builtin_amdgcn_mfma_f32_16x16x32_f16(          \
                    a_[mi], b_[ni], acc[mi][ni], 0, 0, 0);                     \
    } while (0)

    STAGE(0, 0);
    STAGE(1, 1);

    for (int j = 0; j < nt - 1; ++j) {
        asm volatile("s_waitcnt vmcnt(4)" ::: "memory");
        __builtin_amdgcn_s_barrier();
        __builtin_amdgcn_sched_barrier(0);
        if (j + 2 < nt) STAGE((j + 2) % 3, j + 2);
        COMPUTE(j % 3);
    }
    asm volatile("s_waitcnt vmcnt(0)" ::: "memory");
    __builtin_amdgcn_s_barrier();
    __builtin_amdgcn_sched_barrier(0);
    COMPUTE((nt - 1) % 3);

#undef STAGE
#undef COMPUTE

    const int cr0 = (lane >> 4) << 2;
    const int cc = lane & 15;
    float*    Cf = (float*)Cp    + (size_t)z * sC;
    _Float16* Ch = (_Float16*)Cp + (size_t)z * sC;
#pragma unroll
    for (int mi = 0; mi < 4; ++mi) {
#pragma unroll
        for (int ni = 0; ni < 4; ++ni) {
            const int gc = n0 + wn * 64 + ni * 16 + cc;
            if (gc >= Nstore) continue;
            const bool real = gc < Nreal;
            float bb = 0.f;
            if (BIAS) bb = real ? bias[gc] : 0.f;
#pragma unroll
            for (int r = 0; r < 4; ++r) {
                const int gr = m0 + wm * 64 + mi * 16 + cr0 + r;
                if (gr >= M) continue;
                float x = real ? (acc[mi][ni][r] + bb) : 0.f;
                if (TANH) x = fast_tanh(x);
                if (OUT_F16) Ch[(size_t)gr * ldc + gc] = (_Float16)x;
                else         Cf[(size_t)gr * ldc + gc] = x;
            }
        }
    }
}

extern "C" void kernel_launch(void* const* d_in, const int* in_sizes, int n_in,
                              void* d_out, int out_size, void* d_ws, size_t ws_size,
                              hipStream_t stream)
{
    const float* b  = (const float*)d_in[0];
    const float* e  = (const float*)d_in[1];
    const float* Wq = (const float*)d_in[2];
    const float* bq = (const float*)d_in[3];
    const float* Wk = (const float*)d_in[4];
    const float* bk = (const float*)d_in[5];
    const float* Wv = (const float*)d_in[6];
    const float* bv = (const float*)d_in[7];
    float* out = (float*)d_out;

    const int BT = 36928, T = 577, S = 577, Sp = 608, Kb = 800;
    const int Nmg = 1408;   // merged B rows: 800 aug + 608 v-slot

    // ws layout (f16 units): ~212.5 MB total
    _Float16* WqT_h  = (_Float16*)d_ws;                      // 589824
    _Float16* WkT_h  = WqT_h + 589824;                       // 589824
    _Float16* Mt_aug = WkT_h + 589824;                       // 800*768 (B rows 0..799)
    _Float16* Wv_h   = Mt_aug + 614400;                      // 577*768 (B rows 800..1376)
    float*    bias_mg = (float*)(Wv_h + 443136);             // 1408 f32 (2816 hw)
    float*    w2f     = (float*)((_Float16*)bias_mg + 2816); // 768 f32 (1536 hw)
    _Float16* S1    = (_Float16*)w2f + 1536;                 // b_h [BT,768] then e' [BT,800]
    _Float16* S_big = S1 + (size_t)BT * Kb;                  // [BT,1408]
    _Float16* S4    = S_big + (size_t)BT * Nmg;              // attn [BT,608]

    // weight preprocessing
    cvtT2_kernel<<<dim3(24, 24, 2), 256, 0, stream>>>(Wq, WqT_h, Wk, WkT_h);
    cvt8_kernel<<<217, 256, 0, stream>>>(Wv, Wv_h, 55392);
    prep_kernel<<<398, 256, 0, stream>>>(WqT_h, WkT_h, bq, bk, bv, w2f, Mt_aug, bias_mg);
    // Mt = NT(WkT, WqT)  [768x768] -> Mt_aug rows 0..767
    gemm_nt_f16<false, true, false, 0><<<dim3(36, 1, 1), 256, 0, stream>>>(
        WkT_h, WqT_h, nullptr, Mt_aug, 768, 768, 768, 768, 768, 768, 768, 6, 0, 0, 0, 0);

    // b -> f16
    cvt8_kernel<<<2048, 256, 0, stream>>>(b, S1, 3545088);
    // S_big = b_h @ B_merged^T + bias_mg   [BT,1408]  (11 N-tiles, 0 waste)
    gemm_nt_f16<false, true, true, 0><<<dim3(3179, 1, 1), 256, 0, stream>>>(
        S1, Mt_aug, bias_mg, S_big, BT, 1377, Nmg, 768, 768, 768, Nmg, 11, 0, 0, 0, 0);
    // e' (overwrites b_h, dead)
    cvt_e_aug_kernel<<<2048, 256, 0, stream>>>(e, w2f, S1, BT);
    // attn = tanh(NT(S_big[:,0:800], e'))  batched [64][577,608], K=800
    gemm_nt_f16<true, true, false, 1><<<dim3(1600, 1, 1), 256, 0, stream>>>(
        S_big, S1, nullptr, S4, T, S, Sp, Kb, Nmg, Kb, Sp, 5, 25,
        (long long)T * Nmg, (long long)T * Kb, (long long)T * Sp);
    // out = NT(attn, S_big[:,800:1408])  batched [64][577,577] f32, K=608
    gemm_nt_f16<false, false, false, 1><<<dim3(1600, 1, 1), 256, 0, stream>>>(
        S4, S_big + 800, nullptr, out, T, T, T, Sp, Sp, Nmg, T, 5, 25,
        (long long)T * Sp, (long long)T * Nmg, (long long)T * T);
}

// Round 16
// 338.191 us; speedup vs baseline: 1.1635x; 1.0232x over previous
//
#include <hip/hip_runtime.h>
#include <hip/hip_fp16.h>

// Pipeline (all fp16 MFMA, f32 accum), R7-proven 3-stage GEMM structure:
//   Algebraic fusion (R10): q·k^T = b(Wq^T Wk)e^T + b·w1 + (e·w2) + c0.
//   Merged projection (R11): S_big = b_h @ [Mt|w1|0|Wv]^T + bias  [BT,1408]
//     cols 0..799 = bm' (attn A), cols 800..1407 = v (out B).
//   attn = tanh(NT(S_big[,0:800], e'))  batched ; out = NT(attn, S_big[,800:]).
// R16: merged GEMM -> gemm256m: 256x128 (MxN) tile, 8 waves (4M x 2N of
//   64x64 -- per-wave structure IDENTICAL to the proven 128^2 kernel),
//   3-stage counted-vmcnt, 3 loads/stage/thread -> vmcnt(3), LDS 72 KB ->
//   2 blocks/CU = 16 waves/CU (vs 12) for better latency hiding.
//   Batched GEMMs stay 128^2 (256-row tiles would waste 25% at M=577).
// R15: fast tanh epilogue: tanh(x) = 1 - 2*rcp(exp2(2log2e*x)+1).
// XOR-swizzled LDS slots (verified R6): chunk c -> row c>>2, col
// ((c&3)^((c>>3)&3))*8; read lane l row r: chunk r*4 + ((l>>4)^((r>>1)&3)).
// 0 bank conflicts + intact 64B-line write coalescing.
// MODE0 = bijective XCD chunking; MODE1 = batch->XCD co-location.
// NOTE (R8/R12/R13/R14): K=768 too shallow for 8-phase/256^2-BK64 schedules;
// occupancy-rich 3-stage is the right structure here.

typedef _Float16 f16x8 __attribute__((ext_vector_type(8)));
typedef _Float16 f16x4 __attribute__((ext_vector_type(4)));
typedef float f32x4 __attribute__((ext_vector_type(4)));

__global__ void cvt8_kernel(const float* __restrict__ src, _Float16* __restrict__ dst,
                            long long n8) {
    long long i = blockIdx.x * (long long)blockDim.x + threadIdx.x;
    const long long stride = gridDim.x * (long long)blockDim.x;
    for (; i < n8; i += stride) {
        const float4 f0 = ((const float4*)src)[2 * i];
        const float4 f1 = ((const float4*)src)[2 * i + 1];
        f16x8 h;
        h[0] = (_Float16)f0.x; h[1] = (_Float16)f0.y; h[2] = (_Float16)f0.z; h[3] = (_Float16)f0.w;
        h[4] = (_Float16)f1.x; h[5] = (_Float16)f1.y; h[6] = (_Float16)f1.z; h[7] = (_Float16)f1.w;
        ((f16x8*)dst)[i] = h;
    }
}

// two f32 [768,768] -> f16 transposed [768,768] (z selects matrix)
__global__ void cvtT2_kernel(const float* __restrict__ s0, _Float16* __restrict__ d0,
                             const float* __restrict__ s1, _Float16* __restrict__ d1) {
    __shared__ float t[32][33];
    const float* src = blockIdx.z ? s1 : s0;
    _Float16* dst = blockIdx.z ? d1 : d0;
    const int bx = blockIdx.x, by = blockIdx.y;
    const int tx = threadIdx.x & 31, ty = threadIdx.x >> 5;
#pragma unroll
    for (int k = 0; k < 4; ++k) {
        const int r = ty + 8 * k;
        t[r][tx] = src[(size_t)(by * 32 + r) * 768 + bx * 32 + tx];
    }
    __syncthreads();
#pragma unroll
    for (int k = 0; k < 4; ++k) {
        const int r = ty + 8 * k;
        dst[(size_t)(bx * 32 + r) * 768 + by * 32 + tx] = (_Float16)t[tx][r];
    }
}

// w1 -> Mt_aug row 768 ; w2f ; bias_mg[1408] ; zero Mt_aug rows 769..799
__global__ void prep_kernel(const _Float16* __restrict__ WqT, const _Float16* __restrict__ WkT,
                            const float* __restrict__ bq, const float* __restrict__ bk,
                            const float* __restrict__ bv,
                            float* __restrict__ w2f, _Float16* __restrict__ Mt_aug,
                            float* __restrict__ bias_mg) {
    const int wid = blockIdx.x * 4 + (threadIdx.x >> 6);
    const int lane = threadIdx.x & 63;
    if (wid < 768) {                 // w1[wid] = WqT[wid,:]·bk
        float s = 0.f;
        for (int k = 0; k < 12; ++k) s += (float)WqT[(size_t)wid * 768 + lane + 64 * k] * bk[lane + 64 * k];
        for (int o = 32; o; o >>= 1) s += __shfl_xor(s, o);
        if (lane == 0) Mt_aug[(size_t)768 * 768 + wid] = (_Float16)s;
    } else if (wid < 1536) {         // w2[n] = WkT[n,:]·bq
        const int n = wid - 768;
        float s = 0.f;
        for (int k = 0; k < 12; ++k) s += (float)WkT[(size_t)n * 768 + lane + 64 * k] * bq[lane + 64 * k];
        for (int o = 32; o; o >>= 1) s += __shfl_xor(s, o);
        if (lane == 0) w2f[n] = s;
    } else if (wid == 1536) {        // c0 -> bias_mg[768], 1 -> [769], 0 -> 770..799
        float s = 0.f;
        for (int k = 0; k < 12; ++k) s += bq[lane + 64 * k] * bk[lane + 64 * k];
        for (int o = 32; o; o >>= 1) s += __shfl_xor(s, o);
        if (lane < 32) {
            float v = 0.f;
            if (lane == 0) v = s;
            if (lane == 1) v = 1.f;
            bias_mg[768 + lane] = v;
        }
    } else if (wid < 1560) {         // bias_mg: zeros 0..767 ; bv -> 800..1376 ; 0 pads
        const int i = (wid - 1537) * 64 + lane;     // [0,1472)
        if (i < 768) bias_mg[i] = 0.f;
        else {
            const int j = i + 32;                   // 800..1503
            if (j < 1408) bias_mg[j] = (j < 1377) ? bv[j - 800] : 0.f;
        }
    } else if (wid < 1591) {         // zero Mt_aug rows 769..799
        const int r = 769 + (wid - 1560);
        for (int k = 0; k < 12; ++k) Mt_aug[(size_t)r * 768 + lane + 64 * k] = (_Float16)0.f;
    }
}

// e f32 [rows,768] -> e' f16 [rows,800]: cvt + col768=1 + col769=e·w2 + 770..799=0
__global__ void cvt_e_aug_kernel(const float* __restrict__ e, const float* __restrict__ w2f,
                                 _Float16* __restrict__ dst, int rows) {
    const int wpb = blockDim.x >> 6;
    int wid = blockIdx.x * wpb + (threadIdx.x >> 6);
    const int nw = gridDim.x * wpb;
    const int lane = threadIdx.x & 63;
    for (int s = wid; s < rows; s += nw) {
        const float4* er = (const float4*)(e + (size_t)s * 768);
        _Float16* dr = dst + (size_t)s * 800;
        float dot = 0.f;
#pragma unroll
        for (int k = 0; k < 3; ++k) {
            const int idx = lane + 64 * k;
            const float4 v = er[idx];
            const float4 w = ((const float4*)w2f)[idx];
            dot += v.x * w.x + v.y * w.y + v.z * w.z + v.w * w.w;
            f16x4 h;
            h[0] = (_Float16)v.x; h[1] = (_Float16)v.y;
            h[2] = (_Float16)v.z; h[3] = (_Float16)v.w;
            *(f16x4*)(dr + 4 * idx) = h;
        }
        for (int o = 32; o; o >>= 1) dot += __shfl_xor(dot, o);
        if (lane < 32) {
            _Float16 v = (_Float16)0.f;
            if (lane == 0) v = (_Float16)1.f;
            if (lane == 1) v = (_Float16)dot;
            dr[768 + lane] = v;
        }
    }
}

__device__ __forceinline__ void gload16(const _Float16* g, _Float16* l) {
    __builtin_amdgcn_global_load_lds(
        (const __attribute__((address_space(1))) unsigned int*)(g),
        (__attribute__((address_space(3))) unsigned int*)(l),
        16, 0, 0);
}

// overflow-safe fast tanh: 1 - 2*rcp(exp2(2log2e*x)+1)
__device__ __forceinline__ float fast_tanh(float x) {
    const float t = __builtin_amdgcn_exp2f(2.885390081777927f * x);
    return 1.f - 2.f * __builtin_amdgcn_rcpf(t + 1.f);
}

// ======== gemm256m: 256x128 (MxN) / BK=32 / 8-wave 3-stage (merged) =========
// Per-wave structure identical to gemm_nt_f16 (64x64 wave tile, acc[4][4]);
// 3 loads/stage/thread (A x2, B x1) -> vmcnt(3); LDS 72 KB -> 2 blocks/CU.
__global__ __launch_bounds__(512)
void gemm256m(const _Float16* __restrict__ A, const _Float16* __restrict__ Bt,
              const float* __restrict__ bias, _Float16* __restrict__ C,
              int M, int Nreal, int Nstore, int K,
              int lda, int ldb, int ldc, int nTileN)
{
    __shared__ __align__(16) _Float16 lds[3 * 12288];   // 3 x (A 16KB + B 8KB)

    int bid = blockIdx.x;
    {   // bijective XCD chunking (m204)
        const int nwg = gridDim.x;
        const int q8 = nwg >> 3, r8 = nwg & 7;
        const int xcd = bid & 7, loc = bid >> 3;
        bid = (xcd < r8 ? xcd * (q8 + 1) : r8 * (q8 + 1) + (xcd - r8) * q8) + loc;
    }
    const int tm = bid / nTileN, tn = bid - tm * nTileN;
    const int m0 = tm << 8, n0 = tn << 7;

    const int tid = threadIdx.x;
    const int lane = tid & 63;
    const int wid = tid >> 6;
    const int wm = wid >> 1;            // 0..3 M quarter (64 rows)
    const int wn = wid & 1;             // 0..1 N half (64 cols)

    // staging: A chunks tid, tid+512 (rows tid>>2, 128+tid>>2); B chunk tid
    const int r0 = tid >> 2;
    const int c0 = (((tid & 3) ^ ((tid >> 3) & 3)) << 3);
    int ra0 = m0 + r0;        if (ra0 >= M) ra0 = M - 1;
    int ra1 = m0 + 128 + r0;  if (ra1 >= M) ra1 = M - 1;
    int rb0 = n0 + r0;        if (rb0 >= Nreal) rb0 = Nreal - 1;
    const _Float16* pA0 = A + (size_t)ra0 * lda + c0;
    const _Float16* pA1 = A + (size_t)ra1 * lda + c0;
    const _Float16* pB0 = Bt + (size_t)rb0 * ldb + c0;

    const int o0 = tid * 8, o1 = (tid + 512) * 8;

    const int rr = lane & 15;
    const int hh = lane >> 4;
    const int sw = (rr >> 1) & 3;
    const int fAo = ((wm * 64 + rr) * 4 + (hh ^ sw)) * 8;
    const int fBo = ((wn * 64 + rr) * 4 + (hh ^ sw)) * 8;

    const f32x4 z4 = {0.f, 0.f, 0.f, 0.f};
    f32x4 acc[4][4];
#pragma unroll
    for (int i = 0; i < 4; ++i)
#pragma unroll
        for (int j = 0; j < 4; ++j) acc[i][j] = z4;

    const int nt = K >> 5;

#define STAGE(si, kt)                                              \
    do {                                                           \
        _Float16* base_ = lds + (si) * 12288;                      \
        const int ko_ = (kt) << 5;                                 \
        gload16(pA0 + ko_, base_ + o0);                            \
        gload16(pA1 + ko_, base_ + o1);                            \
        gload16(pB0 + ko_, base_ + 8192 + o0);                     \
    } while (0)

#define COMPUTE(si)                                                            \
    do {                                                                       \
        const _Float16* cA_ = lds + (si) * 12288;                              \
        const _Float16* cB_ = cA_ + 8192;                                      \
        f16x8 a_[4], b_[4];                                                    \
        _Pragma("unroll")                                                      \
        for (int mi = 0; mi < 4; ++mi) a_[mi] = *(const f16x8*)(cA_ + fAo + mi * 512); \
        _Pragma("unroll")                                                      \
        for (int ni = 0; ni < 4; ++ni) b_[ni] = *(const f16x8*)(cB_ + fBo + ni * 512); \
        _Pragma("unroll")                                                      \
        for (int mi = 0; mi < 4; ++mi)                                         \
            _Pragma("unroll")                                                  \
            for (int ni = 0; ni < 4; ++ni)                                     \
                acc[mi][ni] = __builtin_amdgcn_mfma_f32_16x16x32_f16(          \
                    a_[mi], b_[ni], acc[mi][ni], 0, 0, 0);                     \
    } while (0)

    STAGE(0, 0);
    STAGE(1, 1);

    for (int j = 0; j < nt - 1; ++j) {
        asm volatile("s_waitcnt vmcnt(3)" ::: "memory");   // tile j's 3 loads done
        __builtin_amdgcn_s_barrier();
        __builtin_amdgcn_sched_barrier(0);
        if (j + 2 < nt) STAGE((j + 2) % 3, j + 2);
        COMPUTE(j % 3);
    }
    asm volatile("s_waitcnt vmcnt(0)" ::: "memory");
    __builtin_amdgcn_s_barrier();
    __builtin_amdgcn_sched_barrier(0);
    COMPUTE((nt - 1) % 3);

#undef STAGE
#undef COMPUTE

    // epilogue: bias -> f16 store (zero padded cols [Nreal, Nstore))
    const int cr0 = (lane >> 4) << 2;
    const int cc = lane & 15;
#pragma unroll
    for (int mi = 0; mi < 4; ++mi) {
#pragma unroll
        for (int ni = 0; ni < 4; ++ni) {
            const int gc = n0 + wn * 64 + ni * 16 + cc;
            if (gc >= Nstore) continue;
            const bool real = gc < Nreal;
            const float bb = real ? bias[gc] : 0.f;
#pragma unroll
            for (int r = 0; r < 4; ++r) {
                const int gr = m0 + wm * 64 + mi * 16 + cr0 + r;
                if (gr >= M) continue;
                const float x = real ? (acc[mi][ni][r] + bb) : 0.f;
                C[(size_t)gr * ldc + gc] = (_Float16)x;
            }
        }
    }
}

// -------- 128x128 / BK=32 / 3-stage counted-vmcnt GEMM (R7, proven) ----------
template<bool TANH, bool OUT_F16, bool BIAS, int MODE>
__global__ __launch_bounds__(256)
void gemm_nt_f16(const _Float16* __restrict__ A, const _Float16* __restrict__ Bt,
                 const float* __restrict__ bias, void* __restrict__ Cp,
                 int M, int Nreal, int Nstore, int K,
                 int lda, int ldb, int ldc, int nTileN, int nTiles,
                 long long sA, long long sB, long long sC)
{
    __shared__ __align__(16) _Float16 lds[3 * 8192];

    int bid = blockIdx.x;
    int z, tm, tn;
    if (MODE == 0) {
        const int nwg = gridDim.x;
        const int q8 = nwg >> 3, r8 = nwg & 7;
        const int xcd = bid & 7, loc = bid >> 3;
        bid = (xcd < r8 ? xcd * (q8 + 1) : r8 * (q8 + 1) + (xcd - r8) * q8) + loc;
        z = 0;
        tm = bid / nTileN; tn = bid - tm * nTileN;
    } else {
        const int xcd = bid & 7, idx = bid >> 3;
        const int g = idx / nTiles, tile = idx - g * nTiles;
        z = g * 8 + xcd;
        tm = tile / nTileN; tn = tile - tm * nTileN;
    }
    const int m0 = tm << 7, n0 = tn << 7;

    const _Float16* Az = A + (size_t)z * sA;
    const _Float16* Bz = Bt + (size_t)z * sB;

    const int tid = threadIdx.x;
    const int lane = tid & 63;
    const int wid = tid >> 6;
    const int wm = wid >> 1, wn = wid & 1;

    const int r0 = tid >> 2;
    const int c0 = (((tid & 3) ^ ((tid >> 3) & 3)) << 3);
    const int rA0 = (m0 + r0      < M ? m0 + r0      : M - 1);
    const int rA1 = (m0 + r0 + 64 < M ? m0 + r0 + 64 : M - 1);
    const int rB0 = (n0 + r0      < Nreal ? n0 + r0      : Nreal - 1);
    const int rB1 = (n0 + r0 + 64 < Nreal ? n0 + r0 + 64 : Nreal - 1);
    const _Float16* pA0 = Az + (size_t)rA0 * lda + c0;
    const _Float16* pA1 = Az + (size_t)rA1 * lda + c0;
    const _Float16* pB0 = Bz + (size_t)rB0 * ldb + c0;
    const _Float16* pB1 = Bz + (size_t)rB1 * ldb + c0;

    const int o0 = tid * 8, o1 = (tid + 256) * 8;

    const int rr = lane & 15;
    const int hh = lane >> 4;
    const int sw = (rr >> 1) & 3;
    const int fAo = ((wm * 64 + rr) * 4 + (hh ^ sw)) * 8;
    const int fBo = ((wn * 64 + rr) * 4 + (hh ^ sw)) * 8;

    const f32x4 z4 = {0.f, 0.f, 0.f, 0.f};
    f32x4 acc[4][4];
#pragma unroll
    for (int i = 0; i < 4; ++i)
#pragma unroll
        for (int j = 0; j < 4; ++j) acc[i][j] = z4;

    const int nt = K >> 5;

#define STAGE(si, kt)                                              \
    do {                                                           \
        _Float16* base_ = lds + (si) * 8192;                       \
        const int ko_ = (kt) << 5;                                 \
        gload16(pA0 + ko_, base_ + o0);                            \
        gload16(pA1 + ko_, base_ + o1);                            \
        gload16(pB0 + ko_, base_ + 4096 + o0);                     \
        gload16(pB1 + ko_, base_ + 4096 + o1);                     \
    } while (0)

#define COMPUTE(si)                                                            \
    do {                                                                       \
        const _Float16* cA_ = lds + (si) * 8192;                               \
        const _Float16* cB_ = cA_ + 4096;                                      \
        f16x8 a_[4], b_[4];                                                    \
        _Pragma("unroll")                                                      \
        for (int mi = 0; mi < 4; ++mi) a_[mi] = *(const f16x8*)(cA_ + fAo + mi * 512); \
        _Pragma("unroll")                                                      \
        for (int ni = 0; ni < 4; ++ni) b_[ni] = *(const f16x8*)(cB_ + fBo + ni * 512); \
        _Pragma("unroll")                                                      \
        for (int mi = 0; mi < 4; ++mi)                                         \
            _Pragma("unroll")                                                  \
            for (int ni = 0; ni < 4; ++ni)                                     \
                acc[mi][ni] = __builtin_amdgcn_mfma_f32_16x16x32_f16(          \
                    a_[mi], b_[ni], acc[mi][ni], 0, 0, 0);                     \
    } while (0)

    STAGE(0, 0);
    STAGE(1, 1);

    for (int j = 0; j < nt - 1; ++j) {
        asm volatile("s_waitcnt vmcnt(4)" ::: "memory");
        __builtin_amdgcn_s_barrier();
        __builtin_amdgcn_sched_barrier(0);
        if (j + 2 < nt) STAGE((j + 2) % 3, j + 2);
        COMPUTE(j % 3);
    }
    asm volatile("s_waitcnt vmcnt(0)" ::: "memory");
    __builtin_amdgcn_s_barrier();
    __builtin_amdgcn_sched_barrier(0);
    COMPUTE((nt - 1) % 3);

#undef STAGE
#undef COMPUTE

    const int cr0 = (lane >> 4) << 2;
    const int cc = lane & 15;
    float*    Cf = (float*)Cp    + (size_t)z * sC;
    _Float16* Ch = (_Float16*)Cp + (size_t)z * sC;
#pragma unroll
    for (int mi = 0; mi < 4; ++mi) {
#pragma unroll
        for (int ni = 0; ni < 4; ++ni) {
            const int gc = n0 + wn * 64 + ni * 16 + cc;
            if (gc >= Nstore) continue;
            const bool real = gc < Nreal;
            float bb = 0.f;
            if (BIAS) bb = real ? bias[gc] : 0.f;
#pragma unroll
            for (int r = 0; r < 4; ++r) {
                const int gr = m0 + wm * 64 + mi * 16 + cr0 + r;
                if (gr >= M) continue;
                float x = real ? (acc[mi][ni][r] + bb) : 0.f;
                if (TANH) x = fast_tanh(x);
                if (OUT_F16) Ch[(size_t)gr * ldc + gc] = (_Float16)x;
                else         Cf[(size_t)gr * ldc + gc] = x;
            }
        }
    }
}

extern "C" void kernel_launch(void* const* d_in, const int* in_sizes, int n_in,
                              void* d_out, int out_size, void* d_ws, size_t ws_size,
                              hipStream_t stream)
{
    const float* b  = (const float*)d_in[0];
    const float* e  = (const float*)d_in[1];
    const float* Wq = (const float*)d_in[2];
    const float* bq = (const float*)d_in[3];
    const float* Wk = (const float*)d_in[4];
    const float* bk = (const float*)d_in[5];
    const float* Wv = (const float*)d_in[6];
    const float* bv = (const float*)d_in[7];
    float* out = (float*)d_out;

    const int BT = 36928, T = 577, S = 577, Sp = 608, Kb = 800;
    const int Nmg = 1408;   // merged B rows: 800 aug + 608 v-slot

    // ws layout (f16 units): ~212.5 MB total
    _Float16* WqT_h  = (_Float16*)d_ws;                      // 589824
    _Float16* WkT_h  = WqT_h + 589824;                       // 589824
    _Float16* Mt_aug = WkT_h + 589824;                       // 800*768 (B rows 0..799)
    _Float16* Wv_h   = Mt_aug + 614400;                      // 577*768 (B rows 800..1376)
    float*    bias_mg = (float*)(Wv_h + 443136);             // 1408 f32 (2816 hw)
    float*    w2f     = (float*)((_Float16*)bias_mg + 2816); // 768 f32 (1536 hw)
    _Float16* S1    = (_Float16*)w2f + 1536;                 // b_h [BT,768] then e' [BT,800]
    _Float16* S_big = S1 + (size_t)BT * Kb;                  // [BT,1408]
    _Float16* S4    = S_big + (size_t)BT * Nmg;              // attn [BT,608]

    // weight preprocessing
    cvtT2_kernel<<<dim3(24, 24, 2), 256, 0, stream>>>(Wq, WqT_h, Wk, WkT_h);
    cvt8_kernel<<<217, 256, 0, stream>>>(Wv, Wv_h, 55392);
    prep_kernel<<<398, 256, 0, stream>>>(WqT_h, WkT_h, bq, bk, bv, w2f, Mt_aug, bias_mg);
    // Mt = NT(WkT, WqT)  [768x768] -> Mt_aug rows 0..767
    gemm_nt_f16<false, true, false, 0><<<dim3(36, 1, 1), 256, 0, stream>>>(
        WkT_h, WqT_h, nullptr, Mt_aug, 768, 768, 768, 768, 768, 768, 768, 6, 0, 0, 0, 0);

    // b -> f16
    cvt8_kernel<<<2048, 256, 0, stream>>>(b, S1, 3545088);
    // S_big = b_h @ B_merged^T + bias_mg   [BT,1408]  (145 x 11 tiles of 256x128)
    gemm256m<<<dim3(1595, 1, 1), 512, 0, stream>>>(
        S1, Mt_aug, bias_mg, S_big, BT, 1377, Nmg, 768, 768, 768, Nmg, 11);
    // e' (overwrites b_h, dead)
    cvt_e_aug_kernel<<<2048, 256, 0, stream>>>(e, w2f, S1, BT);
    // attn = tanh(NT(S_big[:,0:800], e'))  batched [64][577,608], K=800
    gemm_nt_f16<true, true, false, 1><<<dim3(1600, 1, 1), 256, 0, stream>>>(
        S_big, S1, nullptr, S4, T, S, Sp, Kb, Nmg, Kb, Sp, 5, 25,
        (long long)T * Nmg, (long long)T * Kb, (long long)T * Sp);
    // out = NT(attn, S_big[:,800:1408])  batched [64][577,577] f32, K=608
    gemm_nt_f16<false, false, false, 1><<<dim3(1600, 1, 1), 256, 0, stream>>>(
        S4, S_big + 800, nullptr, out, T, T, T, Sp, Sp, Nmg, T, 5, 25,
        (long long)T * Sp, (long long)T * Nmg, (long long)T * T);
}